// Round 6
// baseline (894.647 us; speedup 1.0000x reference)
//
#include <hip/hip_runtime.h>
#include <hip/hip_bf16.h>
#include <stdint.h>

// R12: R11 with the MODE1 epilogue bug fixed — ehT (stage-2 V operand) was
// written WITHOUT the +eln term (edge_h = PV/rsum + eln; R11 only added eln
// on the bf16 edge_h path). Now: lsF = PV*inv -> barrier -> lsF += eln (and
// write edge_h bf16) -> barrier -> transpose ehT from corrected lsF.
// Everything else identical to R11 (conservative __syncthreads sync).

#define B_ 8
#define N_ 4096
#define E_ 2048
#define D_ 256

typedef short bf16x8 __attribute__((ext_vector_type(8)));
typedef float f32x4 __attribute__((ext_vector_type(4)));
typedef unsigned short us8 __attribute__((ext_vector_type(8)));

#define AS1 __attribute__((address_space(1)))
#define AS3 __attribute__((address_space(3)))

__device__ __forceinline__ unsigned short f2bf(float f) {
    union { float f; unsigned int u; } v; v.f = f;
    unsigned int r = v.u + 0x7fffu + ((v.u >> 16) & 1u);
    return (unsigned short)(r >> 16);
}
__device__ __forceinline__ float bf2f(unsigned short h) {
    union { unsigned int u; float f; } v; v.u = ((unsigned int)h) << 16;
    return v.f;
}
__device__ __forceinline__ float waveReduceSum(float v) {
#pragma unroll
    for (int o = 32; o > 0; o >>= 1) v += __shfl_xor(v, o, 64);
    return v;
}

// ---------------- LayerNorm over D=256 -> bf16 ------------------------------
__global__ __launch_bounds__(256) void ln_kernel(const float* __restrict__ x,
                                                 const float* __restrict__ gamma,
                                                 const float* __restrict__ beta,
                                                 unsigned short* __restrict__ yb) {
    __shared__ float red[8];
    const int row = blockIdx.x;
    const int t = threadIdx.x;
    const int lane = t & 63, wid = t >> 6;
    const float v = x[(size_t)row * D_ + t];
    float s = waveReduceSum(v);
    if (lane == 0) red[wid] = s;
    __syncthreads();
    const float mu = (red[0] + red[1] + red[2] + red[3]) * (1.0f / D_);
    const float d = v - mu;
    float s2 = waveReduceSum(d * d);
    if (lane == 0) red[4 + wid] = s2;
    __syncthreads();
    const float var = (red[4] + red[5] + red[6] + red[7]) * (1.0f / D_);
    yb[(size_t)row * D_ + t] = f2bf(gamma[t] * d * rsqrtf(var + 1e-5f) + beta[t]);
}

// ---------------- pack ht -> bitmask: bits[b][e][n>>5] bit (n&31) -----------
__global__ __launch_bounds__(256) void pack_mask(const int* __restrict__ ht,
                                                 uint32_t* __restrict__ bits) {
    __shared__ __align__(8) unsigned char nib[256];
    const int row = blockIdx.x;
    const int t = threadIdx.x;
    const int* hrow = ht + (size_t)row * N_;
    uint32_t* brow = bits + (size_t)row * (N_ / 32);
#pragma unroll
    for (int it = 0; it < 4; ++it) {
        const int4 v = *(const int4*)&hrow[it * 1024 + t * 4];
        unsigned char n = (unsigned char)((v.x > 0) | ((v.y > 0) << 1) |
                                          ((v.z > 0) << 2) | ((v.w > 0) << 3));
        nib[t] = n;
        __syncthreads();
        if (t < 32) {
            uint64_t x = *(const uint64_t*)&nib[t * 8];
            x = (x | (x >> 4)) & 0x00FF00FF00FF00FFull;
            x = (x | (x >> 8)) & 0x0000FFFF0000FFFFull;
            brow[it * 32 + t] = (uint32_t)(x | (x >> 16));
        }
        __syncthreads();
    }
}

// ---------------- fp32 [N,D] -> bf16 [N,D] + bf16 [D,N] ---------------------
__global__ __launch_bounds__(256) void prep_hidden(const float* __restrict__ in,
                                                   unsigned short* __restrict__ hb,
                                                   unsigned short* __restrict__ hT) {
    __shared__ unsigned short tile[64][65];
    const int b = blockIdx.z;
    in += (size_t)b * N_ * D_;
    hb += (size_t)b * N_ * D_;
    hT += (size_t)b * D_ * N_;
    const int n0 = blockIdx.y * 64, d0 = blockIdx.x * 64;
    const int t = threadIdx.x;
    const int tr = t >> 4, tc = (t & 15) * 4;
#pragma unroll
    for (int q = 0; q < 4; ++q) {
        const int rr = q * 16 + tr;
        const float4 f = *(const float4*)&in[(size_t)(n0 + rr) * D_ + d0 + tc];
        unsigned short h0 = f2bf(f.x), h1 = f2bf(f.y), h2 = f2bf(f.z), h3 = f2bf(f.w);
        *(ushort4*)&hb[(size_t)(n0 + rr) * D_ + d0 + tc] = make_ushort4(h0, h1, h2, h3);
        tile[rr][tc + 0] = h0; tile[rr][tc + 1] = h1;
        tile[rr][tc + 2] = h2; tile[rr][tc + 3] = h3;
    }
    __syncthreads();
#pragma unroll
    for (int q = 0; q < 4; ++q) {
        const int cc = q * 16 + tr;
        ushort4 o = make_ushort4(tile[tc + 0][cc], tile[tc + 1][cc],
                                 tile[tc + 2][cc], tile[tc + 3][cc]);
        *(ushort4*)&hT[(size_t)(d0 + cc) * N_ + n0 + tc] = o;
    }
}

// ---------------- tiny: w[D,D] f32 -> wT[D,D] bf16 --------------------------
__global__ __launch_bounds__(256) void cast_wT(const float* __restrict__ w,
                                               unsigned short* __restrict__ wT) {
    const int gid = blockIdx.x * 256 + threadIdx.x;
    const int i = gid >> 8, j = gid & 255;
    wT[j * D_ + i] = f2bf(w[i * D_ + j]);
}

// ---- edge_hsT[d,e] = ehT[d,e] / lsum[e]  (f32 in, bf16 out, [B,D,E]) -------
__global__ __launch_bounds__(256) void scale_ehT(const float* __restrict__ ehT,
                                                 const float* __restrict__ lsum,
                                                 unsigned short* __restrict__ ehs) {
    const size_t base = ((size_t)blockIdx.x * 256 + threadIdx.x) * 8;
    const int b = (int)(base / ((size_t)D_ * E_));
    const int e = (int)(base % E_);
    const float4 f0 = *(const float4*)&ehT[base];
    const float4 f1 = *(const float4*)&ehT[base + 4];
    const float4 l0 = *(const float4*)&lsum[(size_t)b * E_ + e];
    const float4 l1 = *(const float4*)&lsum[(size_t)b * E_ + e + 4];
    us8 o;
    o[0] = f2bf(f0.x / l0.x); o[1] = f2bf(f0.y / l0.y);
    o[2] = f2bf(f0.z / l0.z); o[3] = f2bf(f0.w / l0.w);
    o[4] = f2bf(f1.x / l1.x); o[5] = f2bf(f1.y / l1.y);
    o[6] = f2bf(f1.z / l1.z); o[7] = f2bf(f1.w / l1.w);
    *(us8*)&ehs[base] = o;
}

// ---------------- plain bf16 NT GEMM, K=256 (node_k / edge_k) ---------------
__global__ __launch_bounds__(256) void gemm_bf16(const short* __restrict__ A,
                                                 const short* __restrict__ Bm,
                                                 unsigned short* __restrict__ C) {
    __shared__ __align__(16) short ls[16896];
    short* lsA = ls;
    short* lsB = ls + 8192;
    const int m0 = blockIdx.y * 128, n0 = blockIdx.x * 128;
    const int tid = threadIdx.x, wid = tid >> 6, lane = tid & 63;
    const int l15 = lane & 15, kg = lane >> 4;
    const int wr = wid >> 1, wc = wid & 1;

    int raoff[4], rota[4], rboff[4], rotb[4];
#pragma unroll
    for (int i = 0; i < 4; ++i) {
        const int ra = wr * 64 + i * 16 + l15;
        raoff[i] = ra * 64; rota[i] = kg + (ra >> 1);
        const int rb = wc * 64 + i * 16 + l15;
        rboff[i] = rb * 64; rotb[i] = kg + (rb >> 1);
    }
    const f32x4 zero = {0.f, 0.f, 0.f, 0.f};
    f32x4 acc[4][4];
#pragma unroll
    for (int i = 0; i < 4; ++i)
#pragma unroll
        for (int j = 0; j < 4; ++j) acc[i][j] = zero;

    for (int kt = 0; kt < 256; kt += 64) {
        __syncthreads();
#pragma unroll
        for (int q = 0; q < 4; ++q) {
            const int c = q * 256 + tid;
            const int r = c >> 3;
            const int kc = ((c & 7) - (r >> 1)) & 7;
            const short* ga = A + (size_t)(m0 + r) * 256 + kt + kc * 8;
            __builtin_amdgcn_global_load_lds((const AS1 void*)ga,
                (AS3 void*)(lsA + (q * 256 + wid * 64) * 8), 16, 0, 0);
            const short* gb = Bm + (size_t)(n0 + r) * 256 + kt + kc * 8;
            __builtin_amdgcn_global_load_lds((const AS1 void*)gb,
                (AS3 void*)(lsB + (q * 256 + wid * 64) * 8), 16, 0, 0);
        }
        __syncthreads();
#pragma unroll
        for (int s = 0; s < 2; ++s) {
            bf16x8 fa[4], fb[4];
#pragma unroll
            for (int i = 0; i < 4; ++i)
                fa[i] = *(const bf16x8*)(lsA + raoff[i] + (((s * 4 + rota[i]) & 7) << 3));
#pragma unroll
            for (int j = 0; j < 4; ++j)
                fb[j] = *(const bf16x8*)(lsB + rboff[j] + (((s * 4 + rotb[j]) & 7) << 3));
#pragma unroll
            for (int i = 0; i < 4; ++i)
#pragma unroll
                for (int j = 0; j < 4; ++j)
                    acc[i][j] = __builtin_amdgcn_mfma_f32_16x16x32_bf16(fa[i], fb[j], acc[i][j], 0, 0, 0);
        }
    }
    __syncthreads();
#pragma unroll
    for (int i = 0; i < 4; ++i)
#pragma unroll
        for (int r = 0; r < 4; ++r) {
            const int rowfull = wr * 64 + i * 16 + kg * 4 + r;
#pragma unroll
            for (int j = 0; j < 4; ++j) {
                const int cl = wc * 64 + j * 16 + l15;
                ls[rowfull * 132 + cl] = (short)f2bf(acc[i][j][r]);
            }
        }
    __syncthreads();
#pragma unroll
    for (int si = 0; si < 8; ++si) {
        const int row = (tid >> 4) + si * 16;
        const int col = (tid & 15) * 8;
        us8 val = *(us8*)&ls[row * 132 + col];
        *(us8*)&C[(size_t)(m0 + row) * D_ + n0 + col] = val;
    }
}

// ---------------- fused score->exp->PV kernel -------------------------------
// MODE 0: lsum only (A=edge_k rows e, B1=node_k, loop n; out1=lsum f32[B,E])
// MODE 1: stage 1 (A=eln rows e, B1=node_k, B2=hiddenT, loop n; rsum+div+eln;
//         out1=edge_h bf16 [B,E,D], out2=ehT f32 [B,D,E])
// MODE 2: stage 2 (A=node_k rows n, B1=edge_k, B2=ehsT, loop e;
//         out1=out f32 [B,N,D])
template <int MODE>
__global__ __launch_bounds__(256, 1) void fused_attn(
        const short* __restrict__ A, const short* __restrict__ B1,
        const short* __restrict__ B2, const uint32_t* __restrict__ bits,
        const unsigned short* __restrict__ eln,
        void* __restrict__ out1, float* __restrict__ out2,
        int KN, float scale) {
    // LDS (shorts): b1[2]:0..32767, b2[2]:32768..65535, P:65536..69631,
    // rsx(f32):69632..69887.  MODE0: b1[2] + rsx at 32768.
    __shared__ __align__(16) short ls[(MODE == 0) ? 33024 : 69888];
    const int b = blockIdx.x;      // batch; linear id % 8 == b -> XCD affinity
    const int m0 = blockIdx.y * 64;
    const int MA = (MODE == 2) ? N_ : E_;
    const short* Ab = A + (size_t)b * MA * D_;
    const short* B1b = B1 + (size_t)b * KN * D_;
    const short* B2b = (MODE != 0) ? (B2 + (size_t)b * D_ * KN) : nullptr;
    const uint32_t* bb = bits + (size_t)b * E_ * (N_ / 32);

    const int tid = threadIdx.x, wid = tid >> 6, lane = tid & 63;
    const int l15 = lane & 15, kg = lane >> 4;
    const int wv = wid >> 1, ww = wid & 1;

    // A fragments in registers: rows m0 + wv*32 + mf*16 + l15, full K=256
    bf16x8 fa[2][8];
#pragma unroll
    for (int mf = 0; mf < 2; ++mf) {
        const size_t ar = (size_t)(m0 + wv * 32 + mf * 16 + l15) * D_;
#pragma unroll
        for (int kf = 0; kf < 8; ++kf)
            fa[mf][kf] = *(const bf16x8*)(Ab + ar + (kf * 4 + kg) * 8);
    }

    const f32x4 zero = {0.f, 0.f, 0.f, 0.f};
    f32x4 acco[2][8];
    if (MODE != 0) {
#pragma unroll
        for (int mf = 0; mf < 2; ++mf)
#pragma unroll
            for (int jf = 0; jf < 8; ++jf) acco[mf][jf] = zero;
    }
    float rs[2][4] = {{0.f, 0.f, 0.f, 0.f}, {0.f, 0.f, 0.f, 0.f}};

    short* Pp = ls + 65536;  // MODE!=0 only
    const int NT = KN / 64;

#define STAGE_T(db, tt) do {                                                   \
        const int kt_ = (tt) * 64;                                             \
        short* b1d_ = ls + (db) * 16384;                                       \
        _Pragma("unroll")                                                      \
        for (int q = 0; q < 8; ++q) {                                          \
            const int c_ = q * 256 + tid;                                      \
            const int r_ = c_ >> 5;                                            \
            const int ck_ = (c_ & 31) ^ (r_ & 31);                             \
            __builtin_amdgcn_global_load_lds(                                  \
                (const AS1 void*)(B1b + (size_t)(kt_ + r_) * D_ + ck_ * 8),    \
                (AS3 void*)(b1d_ + (q * 256 + wid * 64) * 8), 16, 0, 0);       \
        }                                                                      \
        if (MODE != 0) {                                                       \
            short* b2d_ = ls + 32768 + (db) * 16384;                           \
            _Pragma("unroll")                                                  \
            for (int q = 0; q < 8; ++q) {                                      \
                const int c_ = q * 256 + tid;                                  \
                const int r_ = c_ >> 3;                                        \
                const int ck_ = (c_ & 7) ^ ((r_ >> 1) & 7);                    \
                __builtin_amdgcn_global_load_lds(                              \
                    (const AS1 void*)(B2b + (size_t)r_ * KN + kt_ + ck_ * 8),  \
                    (AS3 void*)(b2d_ + (q * 256 + wid * 64) * 8), 16, 0, 0);   \
            }                                                                  \
        }                                                                      \
    } while (0)

    STAGE_T(0, 0);
    __syncthreads();

    int cur = 0;
    for (int t = 0; t < NT; ++t) {
        if (t + 1 < NT) STAGE_T(cur ^ 1, t + 1);
        const short* b1c = ls + cur * 16384;
        // ---- score GEMM: accs[mf][jf], rows wv*32+mf*16, cols ww*32+jf*16
        f32x4 accs[2][2];
        accs[0][0] = zero; accs[0][1] = zero; accs[1][0] = zero; accs[1][1] = zero;
        const int rb0 = ww * 32 + l15, rb1 = ww * 32 + 16 + l15;
        const int x0 = kg ^ (rb0 & 31), x1 = kg ^ (rb1 & 31);
#pragma unroll
        for (int kf = 0; kf < 8; ++kf) {
            const bf16x8 fb0 = *(const bf16x8*)(b1c + rb0 * 256 + ((kf * 4) ^ x0) * 8);
            const bf16x8 fb1 = *(const bf16x8*)(b1c + rb1 * 256 + ((kf * 4) ^ x1) * 8);
            accs[0][0] = __builtin_amdgcn_mfma_f32_16x16x32_bf16(fa[0][kf], fb0, accs[0][0], 0, 0, 0);
            accs[1][0] = __builtin_amdgcn_mfma_f32_16x16x32_bf16(fa[1][kf], fb0, accs[1][0], 0, 0, 0);
            accs[0][1] = __builtin_amdgcn_mfma_f32_16x16x32_bf16(fa[0][kf], fb1, accs[0][1], 0, 0, 0);
            accs[1][1] = __builtin_amdgcn_mfma_f32_16x16x32_bf16(fa[1][kf], fb1, accs[1][1], 0, 0, 0);
        }
        // ---- mask + exp (+rs) (+P)
        const int kt0 = t * 64;
        uint64_t mw[2][4];
        uint32_t cw[2];
        if (MODE <= 1) {
#pragma unroll
            for (int mf = 0; mf < 2; ++mf)
#pragma unroll
                for (int r = 0; r < 4; ++r) {
                    const int row = m0 + wv * 32 + mf * 16 + kg * 4 + r;
                    mw[mf][r] = *(const uint64_t*)&bb[(size_t)row * (N_ / 32) + (kt0 >> 5)];
                }
        } else {
#pragma unroll
            for (int jf = 0; jf < 2; ++jf) {
                const int col = kt0 + ww * 32 + jf * 16 + l15;
                cw[jf] = bb[(size_t)col * (N_ / 32) + ((m0 + wv * 32) >> 5)];
            }
        }
#pragma unroll
        for (int mf = 0; mf < 2; ++mf)
#pragma unroll
            for (int jf = 0; jf < 2; ++jf)
#pragma unroll
                for (int r = 0; r < 4; ++r) {
                    float v = accs[mf][jf][r] * scale;
                    uint32_t bit;
                    if (MODE <= 1)
                        bit = (uint32_t)(mw[mf][r] >> (ww * 32 + jf * 16 + l15)) & 1u;
                    else
                        bit = (cw[jf] >> (mf * 16 + kg * 4 + r)) & 1u;
                    v = bit ? __expf(v) : 0.f;
                    if (MODE <= 1) rs[mf][r] += v;
                    if (MODE != 0) {
                        const int prow = wv * 32 + mf * 16 + kg * 4 + r;
                        const int pcol = ww * 32 + jf * 16 + l15;
                        Pp[prow * 64 + (((pcol >> 3) ^ ((prow >> 1) & 7)) * 8) + (pcol & 7)] =
                            (short)f2bf(v);
                    }
                }
        if (MODE != 0) {
            __syncthreads();  // P handoff (also drains next-tile staging)
            // ---- PV GEMM: acco[mf][jf], cols ww*128+jf*16 (d), k = 64 local
            const short* b2c = ls + 32768 + cur * 16384;
            const int pr0 = wv * 32 + l15, pr1 = wv * 32 + 16 + l15;
            const int px0 = kg ^ ((pr0 >> 1) & 7), px1 = kg ^ ((pr1 >> 1) & 7);
#pragma unroll
            for (int kf2 = 0; kf2 < 2; ++kf2) {
                const bf16x8 pa0 = *(const bf16x8*)(Pp + pr0 * 64 + ((kf2 * 4) ^ px0) * 8);
                const bf16x8 pa1 = *(const bf16x8*)(Pp + pr1 * 64 + ((kf2 * 4) ^ px1) * 8);
#pragma unroll
                for (int jf = 0; jf < 8; ++jf) {
                    const int rh = ww * 128 + jf * 16 + l15;
                    const bf16x8 fbh = *(const bf16x8*)(b2c + rh * 64 +
                        (((kf2 * 4 + kg) ^ ((rh >> 1) & 7))) * 8);
                    acco[0][jf] = __builtin_amdgcn_mfma_f32_16x16x32_bf16(pa0, fbh, acco[0][jf], 0, 0, 0);
                    acco[1][jf] = __builtin_amdgcn_mfma_f32_16x16x32_bf16(pa1, fbh, acco[1][jf], 0, 0, 0);
                }
            }
        }
        __syncthreads();  // end of tile: all reads of buf[cur] complete
        cur ^= 1;
    }
#undef STAGE_T

    // ---- epilogues ----
    if (MODE == 0) {
        float* rsx = (float*)(ls + 32768);
#pragma unroll
        for (int mf = 0; mf < 2; ++mf)
#pragma unroll
            for (int r = 0; r < 4; ++r) {
                float s = rs[mf][r];
                s += __shfl_xor(s, 1, 64); s += __shfl_xor(s, 2, 64);
                s += __shfl_xor(s, 4, 64); s += __shfl_xor(s, 8, 64);
                if (l15 == 0) rsx[ww * 64 + wv * 32 + mf * 16 + kg * 4 + r] = s;
            }
        __syncthreads();
        if (tid < 64)
            ((float*)out1)[(size_t)b * E_ + m0 + tid] = rsx[tid] + rsx[64 + tid];
    } else if (MODE == 1) {
        float* rsx = (float*)(ls + 69632);
#pragma unroll
        for (int mf = 0; mf < 2; ++mf)
#pragma unroll
            for (int r = 0; r < 4; ++r) {
                float s = rs[mf][r];
                s += __shfl_xor(s, 1, 64); s += __shfl_xor(s, 2, 64);
                s += __shfl_xor(s, 4, 64); s += __shfl_xor(s, 8, 64);
                if (l15 == 0) rsx[ww * 64 + wv * 32 + mf * 16 + kg * 4 + r] = s;
            }
        __syncthreads();
        float* lsF = (float*)ls;  // [64][261] f32 (aliases b1/b2 region)
#pragma unroll
        for (int mf = 0; mf < 2; ++mf)
#pragma unroll
            for (int r = 0; r < 4; ++r) {
                const int row = wv * 32 + mf * 16 + kg * 4 + r;
                const float inv = 1.0f / (rsx[row] + rsx[64 + row]);
#pragma unroll
                for (int jf = 0; jf < 8; ++jf)
                    lsF[row * 261 + ww * 128 + jf * 16 + l15] = acco[mf][jf][r] * inv;
            }
        __syncthreads();
        // add eln: write edge_h bf16 AND store the corrected value back to lsF
        unsigned short* ehb = (unsigned short*)out1 + (size_t)b * E_ * D_;
        const unsigned short* elnb = eln + (size_t)b * E_ * D_;
#pragma unroll
        for (int p = 0; p < 8; ++p) {
            const int idx = p * 2048 + tid * 8;
            const int row = idx >> 8, col = idx & 255;
            const us8 ev = *(const us8*)&elnb[(size_t)(m0 + row) * D_ + col];
            us8 o;
            float vv[8];
#pragma unroll
            for (int u = 0; u < 8; ++u) {
                vv[u] = lsF[row * 261 + col + u] + bf2f(ev[u]);
                o[u] = f2bf(vv[u]);
            }
            *(us8*)&ehb[(size_t)(m0 + row) * D_ + col] = o;
#pragma unroll
            for (int u = 0; u < 8; ++u)
                lsF[row * 261 + col + u] = vv[u];
        }
        __syncthreads();
        float* ehT = out2 + (size_t)b * D_ * E_;
#pragma unroll
        for (int p = 0; p < 8; ++p) {
            const int idx = p * 2048 + tid * 8;
            const int d = idx >> 6, e8 = idx & 63;
            float4 v0, v1;
            v0.x = lsF[(e8 + 0) * 261 + d]; v0.y = lsF[(e8 + 1) * 261 + d];
            v0.z = lsF[(e8 + 2) * 261 + d]; v0.w = lsF[(e8 + 3) * 261 + d];
            v1.x = lsF[(e8 + 4) * 261 + d]; v1.y = lsF[(e8 + 5) * 261 + d];
            v1.z = lsF[(e8 + 6) * 261 + d]; v1.w = lsF[(e8 + 7) * 261 + d];
            *(float4*)&ehT[(size_t)d * E_ + m0 + e8] = v0;
            *(float4*)&ehT[(size_t)d * E_ + m0 + e8 + 4] = v1;
        }
    } else {
        float* lsF = (float*)ls;  // [64][256] f32
#pragma unroll
        for (int mf = 0; mf < 2; ++mf)
#pragma unroll
            for (int r = 0; r < 4; ++r) {
                const int row = wv * 32 + mf * 16 + kg * 4 + r;
#pragma unroll
                for (int jf = 0; jf < 8; ++jf)
                    lsF[row * 256 + ww * 128 + jf * 16 + l15] = acco[mf][jf][r];
            }
        __syncthreads();
        float* ob = (float*)out1 + (size_t)b * N_ * D_;
#pragma unroll
        for (int p = 0; p < 16; ++p) {
            const int lin = p * 256 + tid;
            const int row = lin >> 6, c4 = (lin & 63) * 4;
            *(float4*)&ob[(size_t)(m0 + row) * D_ + c4] = *(const float4*)&lsF[row * 256 + c4];
        }
    }
}

// ---------------------------------------------------------------------------
extern "C" void kernel_launch(void* const* d_in, const int* in_sizes, int n_in,
                              void* d_out, int out_size, void* d_ws, size_t ws_size,
                              hipStream_t stream) {
    const float* hidden = (const float*)d_in[0];    // [B,N,D]
    const int* ht = (const int*)d_in[1];            // [B,E,N]
    const float* edge_emb = (const float*)d_in[2];  // [B,E,D]
    const float* wnk = (const float*)d_in[3];       // [D,D]
    const float* wek = (const float*)d_in[4];       // [D,D]
    const float* gamma = (const float*)d_in[5];     // [D]
    const float* beta = (const float*)d_in[6];      // [D]
    float* out = (float*)d_out;                     // [B,N,D]
    (void)in_sizes; (void)n_in; (void)out_size; (void)ws_size;

    char* w = (char*)d_ws;
    unsigned short* hidden_bf = (unsigned short*)w;  w += (size_t)B_ * N_ * D_ * 2;
    unsigned short* hiddenT_bf = (unsigned short*)w; w += (size_t)B_ * D_ * N_ * 2;
    unsigned short* node_k_bf = (unsigned short*)w;  w += (size_t)B_ * N_ * D_ * 2;
    unsigned short* eln_bf = (unsigned short*)w;     w += (size_t)B_ * E_ * D_ * 2;
    unsigned short* edge_h_bf = (unsigned short*)w;  w += (size_t)B_ * E_ * D_ * 2;
    float* ehT_f32 = (float*)w;                      w += (size_t)B_ * D_ * E_ * 4;
    unsigned short* ehsT_bf = (unsigned short*)w;    w += (size_t)B_ * D_ * E_ * 2;
    unsigned short* edge_k_bf = (unsigned short*)w;  w += (size_t)B_ * E_ * D_ * 2;
    uint32_t* bits = (uint32_t*)w;                   w += (size_t)B_ * E_ * (N_ / 32) * 4;
    float* lsum = (float*)w;                         w += (size_t)B_ * E_ * 4;
    unsigned short* wnkT = (unsigned short*)w;       w += (size_t)D_ * D_ * 2;
    unsigned short* wekT = (unsigned short*)w;       w += (size_t)D_ * D_ * 2;

    const float scale = 0.0625f;  // 1/sqrt(256)

    // prep
    prep_hidden<<<dim3(D_ / 64, N_ / 64, B_), 256, 0, stream>>>(hidden, hidden_bf, hiddenT_bf);
    cast_wT<<<D_ * D_ / 256, 256, 0, stream>>>(wnk, wnkT);
    cast_wT<<<D_ * D_ / 256, 256, 0, stream>>>(wek, wekT);
    ln_kernel<<<B_ * E_, 256, 0, stream>>>(edge_emb, gamma, beta, eln_bf);
    pack_mask<<<B_ * E_, 256, 0, stream>>>(ht, bits);

    // node_k = hidden @ wnk
    gemm_bf16<<<dim3(D_ / 128, (B_ * N_) / 128), 256, 0, stream>>>(
        (const short*)hidden_bf, (const short*)wnkT, node_k_bf);
    // fused stage 1: edge_h bf16 + ehT f32 (rsum/div/+eln inside)
    fused_attn<1><<<dim3(8, E_ / 64), 256, 0, stream>>>(
        (const short*)eln_bf, (const short*)node_k_bf, (const short*)hiddenT_bf,
        bits, eln_bf, edge_h_bf, ehT_f32, N_, scale);
    // edge_k = edge_h @ wek
    gemm_bf16<<<dim3(D_ / 128, (B_ * E_) / 128), 256, 0, stream>>>(
        (const short*)edge_h_bf, (const short*)wekT, edge_k_bf);
    // lsum[e] = sum_n exp(mask(node_k . edge_k * scale))  (row-sum form)
    fused_attn<0><<<dim3(8, E_ / 64), 256, 0, stream>>>(
        (const short*)edge_k_bf, (const short*)node_k_bf, nullptr,
        bits, nullptr, lsum, nullptr, N_, scale);
    // ehsT[d,e] = ehT/lsum
    scale_ehT<<<(B_ * D_ * E_) / (256 * 8), 256, 0, stream>>>(ehT_f32, lsum, ehsT_bf);
    // fused stage 2: out[n,d] = sum_e exp(s2[n,e]) * ehsT[d,e]
    fused_attn<2><<<dim3(8, N_ / 64), 256, 0, stream>>>(
        (const short*)node_k_bf, (const short*)edge_k_bf, (const short*)ehsT_bf,
        bits, nullptr, out, nullptr, E_, scale);
}

// Round 7
// 843.474 us; speedup vs baseline: 1.0607x; 1.0607x over previous
//
#include <hip/hip_runtime.h>
#include <hip/hip_bf16.h>
#include <stdint.h>

// R13: R12's fusion with 32-row m-tiles + single-buffered staging so LDS is
// ~70KB -> 2 blocks/CU, and grids are 512/512/1024 -> >=2 resident blocks per
// CU. Cross-block overlap hides the stage-drain barriers that strangled R12
// (1 block/CU, MfmaUtil 13.6%). Wave layout: 4 waves = 4 n-quarters (score)
// / 4 d-quarters (PV); P [32][64] shared. Numerics identical to R12.

#define B_ 8
#define N_ 4096
#define E_ 2048
#define D_ 256

typedef short bf16x8 __attribute__((ext_vector_type(8)));
typedef float f32x4 __attribute__((ext_vector_type(4)));
typedef unsigned short us8 __attribute__((ext_vector_type(8)));

#define AS1 __attribute__((address_space(1)))
#define AS3 __attribute__((address_space(3)))

__device__ __forceinline__ unsigned short f2bf(float f) {
    union { float f; unsigned int u; } v; v.f = f;
    unsigned int r = v.u + 0x7fffu + ((v.u >> 16) & 1u);
    return (unsigned short)(r >> 16);
}
__device__ __forceinline__ float bf2f(unsigned short h) {
    union { unsigned int u; float f; } v; v.u = ((unsigned int)h) << 16;
    return v.f;
}
__device__ __forceinline__ float waveReduceSum(float v) {
#pragma unroll
    for (int o = 32; o > 0; o >>= 1) v += __shfl_xor(v, o, 64);
    return v;
}

// ---------------- LayerNorm over D=256 -> bf16 ------------------------------
__global__ __launch_bounds__(256) void ln_kernel(const float* __restrict__ x,
                                                 const float* __restrict__ gamma,
                                                 const float* __restrict__ beta,
                                                 unsigned short* __restrict__ yb) {
    __shared__ float red[8];
    const int row = blockIdx.x;
    const int t = threadIdx.x;
    const int lane = t & 63, wid = t >> 6;
    const float v = x[(size_t)row * D_ + t];
    float s = waveReduceSum(v);
    if (lane == 0) red[wid] = s;
    __syncthreads();
    const float mu = (red[0] + red[1] + red[2] + red[3]) * (1.0f / D_);
    const float d = v - mu;
    float s2 = waveReduceSum(d * d);
    if (lane == 0) red[4 + wid] = s2;
    __syncthreads();
    const float var = (red[4] + red[5] + red[6] + red[7]) * (1.0f / D_);
    yb[(size_t)row * D_ + t] = f2bf(gamma[t] * d * rsqrtf(var + 1e-5f) + beta[t]);
}

// ---------------- pack ht -> bitmask: bits[b][e][n>>5] bit (n&31) -----------
__global__ __launch_bounds__(256) void pack_mask(const int* __restrict__ ht,
                                                 uint32_t* __restrict__ bits) {
    __shared__ __align__(8) unsigned char nib[256];
    const int row = blockIdx.x;
    const int t = threadIdx.x;
    const int* hrow = ht + (size_t)row * N_;
    uint32_t* brow = bits + (size_t)row * (N_ / 32);
#pragma unroll
    for (int it = 0; it < 4; ++it) {
        const int4 v = *(const int4*)&hrow[it * 1024 + t * 4];
        unsigned char n = (unsigned char)((v.x > 0) | ((v.y > 0) << 1) |
                                          ((v.z > 0) << 2) | ((v.w > 0) << 3));
        nib[t] = n;
        __syncthreads();
        if (t < 32) {
            uint64_t x = *(const uint64_t*)&nib[t * 8];
            x = (x | (x >> 4)) & 0x00FF00FF00FF00FFull;
            x = (x | (x >> 8)) & 0x0000FFFF0000FFFFull;
            brow[it * 32 + t] = (uint32_t)(x | (x >> 16));
        }
        __syncthreads();
    }
}

// ---------------- fp32 [N,D] -> bf16 [N,D] + bf16 [D,N] ---------------------
__global__ __launch_bounds__(256) void prep_hidden(const float* __restrict__ in,
                                                   unsigned short* __restrict__ hb,
                                                   unsigned short* __restrict__ hT) {
    __shared__ unsigned short tile[64][65];
    const int b = blockIdx.z;
    in += (size_t)b * N_ * D_;
    hb += (size_t)b * N_ * D_;
    hT += (size_t)b * D_ * N_;
    const int n0 = blockIdx.y * 64, d0 = blockIdx.x * 64;
    const int t = threadIdx.x;
    const int tr = t >> 4, tc = (t & 15) * 4;
#pragma unroll
    for (int q = 0; q < 4; ++q) {
        const int rr = q * 16 + tr;
        const float4 f = *(const float4*)&in[(size_t)(n0 + rr) * D_ + d0 + tc];
        unsigned short h0 = f2bf(f.x), h1 = f2bf(f.y), h2 = f2bf(f.z), h3 = f2bf(f.w);
        *(ushort4*)&hb[(size_t)(n0 + rr) * D_ + d0 + tc] = make_ushort4(h0, h1, h2, h3);
        tile[rr][tc + 0] = h0; tile[rr][tc + 1] = h1;
        tile[rr][tc + 2] = h2; tile[rr][tc + 3] = h3;
    }
    __syncthreads();
#pragma unroll
    for (int q = 0; q < 4; ++q) {
        const int cc = q * 16 + tr;
        ushort4 o = make_ushort4(tile[tc + 0][cc], tile[tc + 1][cc],
                                 tile[tc + 2][cc], tile[tc + 3][cc]);
        *(ushort4*)&hT[(size_t)(d0 + cc) * N_ + n0 + tc] = o;
    }
}

// ---------------- tiny: w[D,D] f32 -> wT[D,D] bf16 --------------------------
__global__ __launch_bounds__(256) void cast_wT(const float* __restrict__ w,
                                               unsigned short* __restrict__ wT) {
    const int gid = blockIdx.x * 256 + threadIdx.x;
    const int i = gid >> 8, j = gid & 255;
    wT[j * D_ + i] = f2bf(w[i * D_ + j]);
}

// ---- edge_hsT[d,e] = ehT[d,e] / lsum[e]  (f32 in, bf16 out, [B,D,E]) -------
__global__ __launch_bounds__(256) void scale_ehT(const float* __restrict__ ehT,
                                                 const float* __restrict__ lsum,
                                                 unsigned short* __restrict__ ehs) {
    const size_t base = ((size_t)blockIdx.x * 256 + threadIdx.x) * 8;
    const int b = (int)(base / ((size_t)D_ * E_));
    const int e = (int)(base % E_);
    const float4 f0 = *(const float4*)&ehT[base];
    const float4 f1 = *(const float4*)&ehT[base + 4];
    const float4 l0 = *(const float4*)&lsum[(size_t)b * E_ + e];
    const float4 l1 = *(const float4*)&lsum[(size_t)b * E_ + e + 4];
    us8 o;
    o[0] = f2bf(f0.x / l0.x); o[1] = f2bf(f0.y / l0.y);
    o[2] = f2bf(f0.z / l0.z); o[3] = f2bf(f0.w / l0.w);
    o[4] = f2bf(f1.x / l1.x); o[5] = f2bf(f1.y / l1.y);
    o[6] = f2bf(f1.z / l1.z); o[7] = f2bf(f1.w / l1.w);
    *(us8*)&ehs[base] = o;
}

// ---------------- plain bf16 NT GEMM, K=256 (node_k / edge_k) ---------------
__global__ __launch_bounds__(256) void gemm_bf16(const short* __restrict__ A,
                                                 const short* __restrict__ Bm,
                                                 unsigned short* __restrict__ C) {
    __shared__ __align__(16) short ls[16896];
    short* lsA = ls;
    short* lsB = ls + 8192;
    const int m0 = blockIdx.y * 128, n0 = blockIdx.x * 128;
    const int tid = threadIdx.x, wid = tid >> 6, lane = tid & 63;
    const int l15 = lane & 15, kg = lane >> 4;
    const int wr = wid >> 1, wc = wid & 1;

    int raoff[4], rota[4], rboff[4], rotb[4];
#pragma unroll
    for (int i = 0; i < 4; ++i) {
        const int ra = wr * 64 + i * 16 + l15;
        raoff[i] = ra * 64; rota[i] = kg + (ra >> 1);
        const int rb = wc * 64 + i * 16 + l15;
        rboff[i] = rb * 64; rotb[i] = kg + (rb >> 1);
    }
    const f32x4 zero = {0.f, 0.f, 0.f, 0.f};
    f32x4 acc[4][4];
#pragma unroll
    for (int i = 0; i < 4; ++i)
#pragma unroll
        for (int j = 0; j < 4; ++j) acc[i][j] = zero;

    for (int kt = 0; kt < 256; kt += 64) {
        __syncthreads();
#pragma unroll
        for (int q = 0; q < 4; ++q) {
            const int c = q * 256 + tid;
            const int r = c >> 3;
            const int kc = ((c & 7) - (r >> 1)) & 7;
            const short* ga = A + (size_t)(m0 + r) * 256 + kt + kc * 8;
            __builtin_amdgcn_global_load_lds((const AS1 void*)ga,
                (AS3 void*)(lsA + (q * 256 + wid * 64) * 8), 16, 0, 0);
            const short* gb = Bm + (size_t)(n0 + r) * 256 + kt + kc * 8;
            __builtin_amdgcn_global_load_lds((const AS1 void*)gb,
                (AS3 void*)(lsB + (q * 256 + wid * 64) * 8), 16, 0, 0);
        }
        __syncthreads();
#pragma unroll
        for (int s = 0; s < 2; ++s) {
            bf16x8 fa[4], fb[4];
#pragma unroll
            for (int i = 0; i < 4; ++i)
                fa[i] = *(const bf16x8*)(lsA + raoff[i] + (((s * 4 + rota[i]) & 7) << 3));
#pragma unroll
            for (int j = 0; j < 4; ++j)
                fb[j] = *(const bf16x8*)(lsB + rboff[j] + (((s * 4 + rotb[j]) & 7) << 3));
#pragma unroll
            for (int i = 0; i < 4; ++i)
#pragma unroll
                for (int j = 0; j < 4; ++j)
                    acc[i][j] = __builtin_amdgcn_mfma_f32_16x16x32_bf16(fa[i], fb[j], acc[i][j], 0, 0, 0);
        }
    }
    __syncthreads();
#pragma unroll
    for (int i = 0; i < 4; ++i)
#pragma unroll
        for (int r = 0; r < 4; ++r) {
            const int rowfull = wr * 64 + i * 16 + kg * 4 + r;
#pragma unroll
            for (int j = 0; j < 4; ++j) {
                const int cl = wc * 64 + j * 16 + l15;
                ls[rowfull * 132 + cl] = (short)f2bf(acc[i][j][r]);
            }
        }
    __syncthreads();
#pragma unroll
    for (int si = 0; si < 8; ++si) {
        const int row = (tid >> 4) + si * 16;
        const int col = (tid & 15) * 8;
        us8 val = *(us8*)&ls[row * 132 + col];
        *(us8*)&C[(size_t)(m0 + row) * D_ + n0 + col] = val;
    }
}

// ---------------- fused score->exp->PV kernel (32-row m-tiles) --------------
// MODE 0: lsum only (A=edge_k rows e, B1=node_k, loop n; out1=lsum f32[B,E])
// MODE 1: stage 1 (A=eln, B1=node_k, B2=hiddenT, loop n; rsum+div+eln;
//         out1=edge_h bf16 [B,E,D], out2=ehT f32 [B,D,E])
// MODE 2: stage 2 (A=node_k rows n, B1=edge_k, B2=ehsT, loop e;
//         out1=out f32 [B,N,D])
// Wave layout: 4 waves = 4 n-quarters (score cols ww*16) / 4 d-quarters (PV
// cols ww*64). LDS: b1 32KB + b2 32KB + P 4KB + rsx (single-buffered) ~70KB
// -> 2 blocks/CU.
template <int MODE>
__global__ __launch_bounds__(256, 2) void fused_attn(
        const short* __restrict__ A, const short* __restrict__ B1,
        const short* __restrict__ B2, const uint32_t* __restrict__ bits,
        const unsigned short* __restrict__ eln,
        void* __restrict__ out1, float* __restrict__ out2,
        int KN, float scale) {
    // shorts: b1:0..16383, b2:16384..32767, P:32768..34815, rsx:34816..35071
    // MODE0: b1:0..16383, rsx at 16384.
    __shared__ __align__(16) short ls[(MODE == 0) ? 16640 : 35072];
    const int b = blockIdx.x;      // batch; linear id % 8 == b -> XCD affinity
    const int m0 = blockIdx.y * 32;
    const int MA = (MODE == 2) ? N_ : E_;
    const short* Ab = A + (size_t)b * MA * D_;
    const short* B1b = B1 + (size_t)b * KN * D_;
    const short* B2b = (MODE != 0) ? (B2 + (size_t)b * D_ * KN) : nullptr;
    const uint32_t* bb = bits + (size_t)b * E_ * (N_ / 32);

    const int tid = threadIdx.x, wid = tid >> 6, lane = tid & 63;
    const int l15 = lane & 15, kg = lane >> 4;
    const int ww = wid;  // wave = n-quarter (score) / d-quarter (PV)

    // A fragments in registers: rows m0 + mf*16 + l15, full K=256
    bf16x8 fa[2][8];
#pragma unroll
    for (int mf = 0; mf < 2; ++mf) {
        const size_t ar = (size_t)(m0 + mf * 16 + l15) * D_;
#pragma unroll
        for (int kf = 0; kf < 8; ++kf)
            fa[mf][kf] = *(const bf16x8*)(Ab + ar + (kf * 4 + kg) * 8);
    }

    const f32x4 zero = {0.f, 0.f, 0.f, 0.f};
    f32x4 acco[2][4];
    if (MODE != 0) {
#pragma unroll
        for (int mf = 0; mf < 2; ++mf)
#pragma unroll
            for (int jf = 0; jf < 4; ++jf) acco[mf][jf] = zero;
    }
    float rs[2][4] = {{0.f, 0.f, 0.f, 0.f}, {0.f, 0.f, 0.f, 0.f}};

    short* Pp = ls + 32768;  // MODE!=0 only
    const int NT = KN / 64;

    for (int t = 0; t < NT; ++t) {
        // ---- stage tile t (single buffer; prev tile's reads done at loop-end
        // barrier / trivially for t=0)
        {
            const int kt_ = t * 64;
#pragma unroll
            for (int q = 0; q < 8; ++q) {
                const int c_ = q * 256 + tid;
                const int r_ = c_ >> 5;
                const int ck_ = (c_ & 31) ^ (r_ & 31);
                __builtin_amdgcn_global_load_lds(
                    (const AS1 void*)(B1b + (size_t)(kt_ + r_) * D_ + ck_ * 8),
                    (AS3 void*)(ls + (q * 256 + wid * 64) * 8), 16, 0, 0);
            }
            if (MODE != 0) {
#pragma unroll
                for (int q = 0; q < 8; ++q) {
                    const int c_ = q * 256 + tid;
                    const int r_ = c_ >> 3;
                    const int ck_ = (c_ & 7) ^ ((r_ >> 1) & 7);
                    __builtin_amdgcn_global_load_lds(
                        (const AS1 void*)(B2b + (size_t)r_ * KN + kt_ + ck_ * 8),
                        (AS3 void*)(ls + 16384 + (q * 256 + wid * 64) * 8), 16, 0, 0);
                }
            }
        }
        __syncthreads();  // drain staging

        // ---- score GEMM: accs[mf], rows m0+mf*16, cols t*64 + ww*16
        f32x4 accs[2];
        accs[0] = zero; accs[1] = zero;
        const int rb = ww * 16 + l15;
        const int xb = kg ^ (rb & 31);
#pragma unroll
        for (int kf = 0; kf < 8; ++kf) {
            const bf16x8 fb = *(const bf16x8*)(ls + rb * 256 + ((kf * 4) ^ xb) * 8);
            accs[0] = __builtin_amdgcn_mfma_f32_16x16x32_bf16(fa[0][kf], fb, accs[0], 0, 0, 0);
            accs[1] = __builtin_amdgcn_mfma_f32_16x16x32_bf16(fa[1][kf], fb, accs[1], 0, 0, 0);
        }
        // ---- mask + exp (+rs) (+P)
        const int kt0 = t * 64;
        uint64_t mw[2][4];
        uint32_t cw;
        if (MODE <= 1) {
#pragma unroll
            for (int mf = 0; mf < 2; ++mf)
#pragma unroll
                for (int r = 0; r < 4; ++r) {
                    const int row = m0 + mf * 16 + kg * 4 + r;
                    mw[mf][r] = *(const uint64_t*)&bb[(size_t)row * (N_ / 32) + (kt0 >> 5)];
                }
        } else {
            const int col = kt0 + ww * 16 + l15;
            cw = bb[(size_t)col * (N_ / 32) + (m0 >> 5)];
        }
#pragma unroll
        for (int mf = 0; mf < 2; ++mf)
#pragma unroll
            for (int r = 0; r < 4; ++r) {
                float v = accs[mf][r] * scale;
                uint32_t bit;
                if (MODE <= 1)
                    bit = (uint32_t)(mw[mf][r] >> (ww * 16 + l15)) & 1u;
                else
                    bit = (cw >> (mf * 16 + kg * 4 + r)) & 1u;
                v = bit ? __expf(v) : 0.f;
                if (MODE <= 1) rs[mf][r] += v;
                if (MODE != 0) {
                    const int prow = mf * 16 + kg * 4 + r;
                    const int pcol = ww * 16 + l15;
                    Pp[prow * 64 + (((pcol >> 3) ^ ((prow >> 1) & 7)) * 8) + (pcol & 7)] =
                        (short)f2bf(v);
                }
            }
        if (MODE != 0) {
            __syncthreads();  // P visible (staging already drained)
            // ---- PV GEMM: acco[mf][jf], d-cols ww*64+jf*16, k = 64 local
            const short* b2c = ls + 16384;
            const int pr0 = l15, pr1 = 16 + l15;
            const int px0 = kg ^ ((pr0 >> 1) & 7), px1 = kg ^ ((pr1 >> 1) & 7);
#pragma unroll
            for (int kf2 = 0; kf2 < 2; ++kf2) {
                const bf16x8 pa0 = *(const bf16x8*)(Pp + pr0 * 64 + (((kf2 * 4) ^ px0)) * 8);
                const bf16x8 pa1 = *(const bf16x8*)(Pp + pr1 * 64 + (((kf2 * 4) ^ px1)) * 8);
#pragma unroll
                for (int jf = 0; jf < 4; ++jf) {
                    const int rh = ww * 64 + jf * 16 + l15;
                    const bf16x8 fbh = *(const bf16x8*)(b2c + rh * 64 +
                        (((kf2 * 4 + kg) ^ ((rh >> 1) & 7))) * 8);
                    acco[0][jf] = __builtin_amdgcn_mfma_f32_16x16x32_bf16(pa0, fbh, acco[0][jf], 0, 0, 0);
                    acco[1][jf] = __builtin_amdgcn_mfma_f32_16x16x32_bf16(pa1, fbh, acco[1][jf], 0, 0, 0);
                }
            }
        }
        __syncthreads();  // all reads of b1/b2/P done -> next stage may write
    }

    // ---- epilogues ----
    if (MODE == 0) {
        float* rsx = (float*)(ls + 16384);  // [4][32]
#pragma unroll
        for (int mf = 0; mf < 2; ++mf)
#pragma unroll
            for (int r = 0; r < 4; ++r) {
                float s = rs[mf][r];
                s += __shfl_xor(s, 1, 64); s += __shfl_xor(s, 2, 64);
                s += __shfl_xor(s, 4, 64); s += __shfl_xor(s, 8, 64);
                if (l15 == 0) rsx[ww * 32 + mf * 16 + kg * 4 + r] = s;
            }
        __syncthreads();
        if (tid < 32)
            ((float*)out1)[(size_t)b * E_ + m0 + tid] =
                rsx[tid] + rsx[32 + tid] + rsx[64 + tid] + rsx[96 + tid];
    } else if (MODE == 1) {
        float* rsx = (float*)(ls + 34816);  // [4][32]
#pragma unroll
        for (int mf = 0; mf < 2; ++mf)
#pragma unroll
            for (int r = 0; r < 4; ++r) {
                float s = rs[mf][r];
                s += __shfl_xor(s, 1, 64); s += __shfl_xor(s, 2, 64);
                s += __shfl_xor(s, 4, 64); s += __shfl_xor(s, 8, 64);
                if (l15 == 0) rsx[ww * 32 + mf * 16 + kg * 4 + r] = s;
            }
        __syncthreads();
        float* lsF = (float*)ls;  // [32][261] f32 (aliases b1/b2 region)
#pragma unroll
        for (int mf = 0; mf < 2; ++mf)
#pragma unroll
            for (int r = 0; r < 4; ++r) {
                const int row = mf * 16 + kg * 4 + r;
                const float inv = 1.0f /
                    (rsx[row] + rsx[32 + row] + rsx[64 + row] + rsx[96 + row]);
#pragma unroll
                for (int jf = 0; jf < 4; ++jf)
                    lsF[row * 261 + ww * 64 + jf * 16 + l15] = acco[mf][jf][r] * inv;
            }
        __syncthreads();
        // add eln: write edge_h bf16 AND store corrected value back to lsF
        unsigned short* ehb = (unsigned short*)out1 + (size_t)b * E_ * D_;
        const unsigned short* elnb = eln + (size_t)b * E_ * D_;
#pragma unroll
        for (int p = 0; p < 4; ++p) {
            const int idx = p * 2048 + tid * 8;
            const int row = idx >> 8, col = idx & 255;
            const us8 ev = *(const us8*)&elnb[(size_t)(m0 + row) * D_ + col];
            us8 o;
            float vv[8];
#pragma unroll
            for (int u = 0; u < 8; ++u) {
                vv[u] = lsF[row * 261 + col + u] + bf2f(ev[u]);
                o[u] = f2bf(vv[u]);
            }
            *(us8*)&ehb[(size_t)(m0 + row) * D_ + col] = o;
#pragma unroll
            for (int u = 0; u < 8; ++u)
                lsF[row * 261 + col + u] = vv[u];
        }
        __syncthreads();
        float* ehT = out2 + (size_t)b * D_ * E_;
#pragma unroll
        for (int p = 0; p < 4; ++p) {
            const int idx = p * 2048 + tid * 8;
            const int d = idx >> 5, e8 = idx & 31;
            float4 v0, v1;
            v0.x = lsF[(e8 + 0) * 261 + d]; v0.y = lsF[(e8 + 1) * 261 + d];
            v0.z = lsF[(e8 + 2) * 261 + d]; v0.w = lsF[(e8 + 3) * 261 + d];
            v1.x = lsF[(e8 + 4) * 261 + d]; v1.y = lsF[(e8 + 5) * 261 + d];
            v1.z = lsF[(e8 + 6) * 261 + d]; v1.w = lsF[(e8 + 7) * 261 + d];
            *(float4*)&ehT[(size_t)d * E_ + m0 + e8] = v0;
            *(float4*)&ehT[(size_t)d * E_ + m0 + e8 + 4] = v1;
        }
    } else {
        float* lsF = (float*)ls;  // [32][256] f32
#pragma unroll
        for (int mf = 0; mf < 2; ++mf)
#pragma unroll
            for (int r = 0; r < 4; ++r) {
                const int row = mf * 16 + kg * 4 + r;
#pragma unroll
                for (int jf = 0; jf < 4; ++jf)
                    lsF[row * 256 + ww * 64 + jf * 16 + l15] = acco[mf][jf][r];
            }
        __syncthreads();
        float* ob = (float*)out1 + (size_t)b * N_ * D_;
#pragma unroll
        for (int p = 0; p < 8; ++p) {
            const int lin = p * 256 + tid;
            const int row = lin >> 6, c4 = (lin & 63) * 4;
            *(float4*)&ob[(size_t)(m0 + row) * D_ + c4] = *(const float4*)&lsF[row * 256 + c4];
        }
    }
}

// ---------------------------------------------------------------------------
extern "C" void kernel_launch(void* const* d_in, const int* in_sizes, int n_in,
                              void* d_out, int out_size, void* d_ws, size_t ws_size,
                              hipStream_t stream) {
    const float* hidden = (const float*)d_in[0];    // [B,N,D]
    const int* ht = (const int*)d_in[1];            // [B,E,N]
    const float* edge_emb = (const float*)d_in[2];  // [B,E,D]
    const float* wnk = (const float*)d_in[3];       // [D,D]
    const float* wek = (const float*)d_in[4];       // [D,D]
    const float* gamma = (const float*)d_in[5];     // [D]
    const float* beta = (const float*)d_in[6];      // [D]
    float* out = (float*)d_out;                     // [B,N,D]
    (void)in_sizes; (void)n_in; (void)out_size; (void)ws_size;

    char* w = (char*)d_ws;
    unsigned short* hidden_bf = (unsigned short*)w;  w += (size_t)B_ * N_ * D_ * 2;
    unsigned short* hiddenT_bf = (unsigned short*)w; w += (size_t)B_ * D_ * N_ * 2;
    unsigned short* node_k_bf = (unsigned short*)w;  w += (size_t)B_ * N_ * D_ * 2;
    unsigned short* eln_bf = (unsigned short*)w;     w += (size_t)B_ * E_ * D_ * 2;
    unsigned short* edge_h_bf = (unsigned short*)w;  w += (size_t)B_ * E_ * D_ * 2;
    float* ehT_f32 = (float*)w;                      w += (size_t)B_ * D_ * E_ * 4;
    unsigned short* ehsT_bf = (unsigned short*)w;    w += (size_t)B_ * D_ * E_ * 2;
    unsigned short* edge_k_bf = (unsigned short*)w;  w += (size_t)B_ * E_ * D_ * 2;
    uint32_t* bits = (uint32_t*)w;                   w += (size_t)B_ * E_ * (N_ / 32) * 4;
    float* lsum = (float*)w;                         w += (size_t)B_ * E_ * 4;
    unsigned short* wnkT = (unsigned short*)w;       w += (size_t)D_ * D_ * 2;
    unsigned short* wekT = (unsigned short*)w;       w += (size_t)D_ * D_ * 2;

    const float scale = 0.0625f;  // 1/sqrt(256)

    // prep
    prep_hidden<<<dim3(D_ / 64, N_ / 64, B_), 256, 0, stream>>>(hidden, hidden_bf, hiddenT_bf);
    cast_wT<<<D_ * D_ / 256, 256, 0, stream>>>(wnk, wnkT);
    cast_wT<<<D_ * D_ / 256, 256, 0, stream>>>(wek, wekT);
    ln_kernel<<<B_ * E_, 256, 0, stream>>>(edge_emb, gamma, beta, eln_bf);
    pack_mask<<<B_ * E_, 256, 0, stream>>>(ht, bits);

    // node_k = hidden @ wnk
    gemm_bf16<<<dim3(D_ / 128, (B_ * N_) / 128), 256, 0, stream>>>(
        (const short*)hidden_bf, (const short*)wnkT, node_k_bf);
    // fused stage 1: edge_h bf16 + ehT f32 (rsum/div/+eln inside)
    fused_attn<1><<<dim3(8, E_ / 32), 256, 0, stream>>>(
        (const short*)eln_bf, (const short*)node_k_bf, (const short*)hiddenT_bf,
        bits, eln_bf, edge_h_bf, ehT_f32, N_, scale);
    // edge_k = edge_h @ wek
    gemm_bf16<<<dim3(D_ / 128, (B_ * E_) / 128), 256, 0, stream>>>(
        (const short*)edge_h_bf, (const short*)wekT, edge_k_bf);
    // lsum[e] = sum_n exp(mask(node_k . edge_k * scale))  (row-sum form)
    fused_attn<0><<<dim3(8, E_ / 32), 256, 0, stream>>>(
        (const short*)edge_k_bf, (const short*)node_k_bf, nullptr,
        bits, nullptr, lsum, nullptr, N_, scale);
    // ehsT[d,e] = ehT/lsum
    scale_ehT<<<(B_ * D_ * E_) / (256 * 8), 256, 0, stream>>>(ehT_f32, lsum, ehsT_bf);
    // fused stage 2: out[n,d] = sum_e exp(s2[n,e]) * ehsT[d,e]
    fused_attn<2><<<dim3(8, N_ / 32), 256, 0, stream>>>(
        (const short*)node_k_bf, (const short*)edge_k_bf, (const short*)ehsT_bf,
        bits, nullptr, out, nullptr, E_, scale);
}